// Round 14
// baseline (288.965 us; speedup 1.0000x reference)
//
#include <hip/hip_runtime.h>
#include <hip/hip_bf16.h>

#define N_NODES 100000
#define N_EDGES 1600000
#define F_IN 128
#define F_HID 256
#define F_OUT 128

typedef unsigned short ushort_t;
typedef __attribute__((ext_vector_type(4))) float f32x4;
typedef __attribute__((ext_vector_type(8))) short bf16x8;

#define GAS __attribute__((address_space(1)))
#define LAS __attribute__((address_space(3)))

__device__ __forceinline__ float bf2f(ushort_t u) {
    unsigned int x = ((unsigned int)u) << 16;
    return __builtin_bit_cast(float, x);
}
__device__ __forceinline__ ushort_t f2bf(float f) {
    unsigned int x = __builtin_bit_cast(unsigned int, f);
    unsigned int r = (x + 0x7fffu + ((x >> 16) & 1u)) >> 16;
    return (ushort_t)r;
}

// ---------------- bucket-sort CSR build (round-11, unchanged) ----------------
#define NBUCK ((N_NODES + 255) >> 8)  // 391
#define CHUNK 4096

__global__ __launch_bounds__(256) void bucket_count_kernel(
    const int* __restrict__ dst, int* __restrict__ bucket_cnt, int n) {
    __shared__ int hist[NBUCK];
    int tid = threadIdx.x;
    int e0 = blockIdx.x * CHUNK;
    int cnt = n - e0; if (cnt > CHUNK) cnt = CHUNK;
    for (int b = tid; b < NBUCK; b += 256) hist[b] = 0;
    __syncthreads();
    for (int i = tid; i < cnt; i += 256) {
        int d = __builtin_nontemporal_load(dst + e0 + i);
        atomicAdd(&hist[d >> 8], 1);
    }
    __syncthreads();
    for (int b = tid; b < NBUCK; b += 256)
        if (hist[b]) atomicAdd(&bucket_cnt[b], hist[b]);
}

__global__ __launch_bounds__(512) void bucket_scan_kernel(
    const int* __restrict__ bucket_cnt, int* __restrict__ bbase,
    int* __restrict__ bcursor, int* __restrict__ rowptr) {
    __shared__ int tmp[512];
    int tid = threadIdx.x;
    int v = (tid < NBUCK) ? bucket_cnt[tid] : 0;
    tmp[tid] = v;
    __syncthreads();
#pragma unroll
    for (int off = 1; off < 512; off <<= 1) {
        int t = (tid >= off) ? tmp[tid - off] : 0;
        __syncthreads();
        tmp[tid] += t;
        __syncthreads();
    }
    if (tid < NBUCK) {
        int base = tmp[tid] - v;
        bbase[tid] = base;
        bcursor[tid] = base;
    }
    if (tid == 0) {
        bbase[NBUCK] = N_EDGES;
        rowptr[N_NODES] = N_EDGES;
    }
}

__global__ __launch_bounds__(256) void bin_edges_kernel(
    const int* __restrict__ src, const int* __restrict__ dst,
    int* __restrict__ bcursor, unsigned int* __restrict__ pairs, int n) {
    __shared__ int sdst[CHUNK];
    __shared__ int ssrc[CHUNK];
    __shared__ int hist[NBUCK];
    __shared__ int resv[NBUCK];
    int tid = threadIdx.x;
    int e0 = blockIdx.x * CHUNK;
    int cnt = n - e0; if (cnt > CHUNK) cnt = CHUNK;
    for (int b = tid; b < NBUCK; b += 256) hist[b] = 0;
    __syncthreads();
    for (int i = tid; i < cnt; i += 256) {
        int d = __builtin_nontemporal_load(dst + e0 + i);
        int s = __builtin_nontemporal_load(src + e0 + i);
        sdst[i] = d;
        ssrc[i] = s;
        atomicAdd(&hist[d >> 8], 1);
    }
    __syncthreads();
    for (int b = tid; b < NBUCK; b += 256) {
        int h = hist[b];
        resv[b] = h ? atomicAdd(&bcursor[b], h) : 0;
        hist[b] = 0;
    }
    __syncthreads();
    for (int i = tid; i < cnt; i += 256) {
        int d = sdst[i], s = ssrc[i];
        int b = d >> 8;
        int off = atomicAdd(&hist[b], 1);
        pairs[resv[b] + off] = ((unsigned)(d & 255) << 17) | (unsigned)s;
    }
}

__global__ __launch_bounds__(256) void sort_bucket_kernel(
    const unsigned int* __restrict__ pairs, const int* __restrict__ bbase,
    int* __restrict__ rowptr, float* __restrict__ invdeg,
    int* __restrict__ csr_src, int nNodes) {
    __shared__ int lcnt[256];
    __shared__ int lrp[256];
    int tid = threadIdx.x;
    int base = blockIdx.x << 8;
    int nn = nNodes - base; if (nn > 256) nn = 256;
    lcnt[tid] = 0;
    __syncthreads();
    int e0 = bbase[blockIdx.x], e1 = bbase[blockIdx.x + 1];
    for (int i = e0 + tid; i < e1; i += 256)
        atomicAdd(&lcnt[pairs[i] >> 17], 1);
    __syncthreads();
    int v = lcnt[tid];
    lrp[tid] = v;
    __syncthreads();
#pragma unroll
    for (int off = 1; off < 256; off <<= 1) {
        int t = (tid >= off) ? lrp[tid - off] : 0;
        __syncthreads();
        lrp[tid] += t;
        __syncthreads();
    }
    lcnt[tid] = 0;
    lrp[tid] = lrp[tid] - v + e0;
    if (tid < nn) {
        rowptr[base + tid] = lrp[tid];
        invdeg[base + tid] = 1.0f / fmaxf((float)v, 1.0f);
    }
    __syncthreads();
    for (int i = e0 + tid; i < e1; i += 256) {
        unsigned pv = pairs[i];
        int j = (int)(pv >> 17);
        int off = atomicAdd(&lcnt[j], 1);
        csr_src[lrp[j] + off] = (int)(pv & 0x1FFFFu);
    }
}

// ---------------- fp32 -> bf16 converts ----------------
__global__ __launch_bounds__(256) void convert_x_kernel(const float* __restrict__ x,
                                                        ushort_t* __restrict__ xb, int n4) {
    int i = blockIdx.x * 256 + threadIdx.x;
    if (i >= n4) return;
    int e = i * 4;
    f32x4 v = __builtin_nontemporal_load((const f32x4*)(x + e));
    ushort4 o;
    o.x = f2bf(v.x); o.y = f2bf(v.y); o.z = f2bf(v.z); o.w = f2bf(v.w);
    *(ushort4*)(xb + e) = o;
}

__global__ __launch_bounds__(256) void wtransK_kernel(const float* __restrict__ W1,
                                                      const float* __restrict__ W2,
                                                      ushort_t* __restrict__ Wt,
                                                      int Kx, int Ktot, int N) {
    int i = blockIdx.x * 256 + threadIdx.x;
    if (i >= N * Ktot) return;
    int n = i / Ktot, k = i - n * Ktot;
    float v = (k < Kx) ? W1[(size_t)k * N + n] : W2[(size_t)(k - Kx) * N + n];
    Wt[(size_t)n * Ktot + k] = f2bf(v);
}

__global__ __launch_bounds__(256) void wtransN_kernel(const float* __restrict__ Wa,
                                                      const float* __restrict__ Wb,
                                                      ushort_t* __restrict__ Wt,
                                                      int K, int Nh) {
    int i = blockIdx.x * 256 + threadIdx.x;
    if (i >= 2 * Nh * K) return;
    int n = i / K, k = i - n * K;
    const float* W = (n < Nh) ? Wa : Wb;
    int nn = (n < Nh) ? n : n - Nh;
    Wt[(size_t)n * K + k] = f2bf(W[(size_t)k * Nh + nn]);
}

// ---------------- persistent dual-node gather (round-12, unchanged) ---------
#define ACC8(arr, v)                                                \
    arr[0] += bf2f((ushort_t)((v).x & 0xffffu));                    \
    arr[1] += bf2f((ushort_t)((v).x >> 16));                        \
    arr[2] += bf2f((ushort_t)((v).y & 0xffffu));                    \
    arr[3] += bf2f((ushort_t)((v).y >> 16));                        \
    arr[4] += bf2f((ushort_t)((v).z & 0xffffu));                    \
    arr[5] += bf2f((ushort_t)((v).z >> 16));                        \
    arr[6] += bf2f((ushort_t)((v).w & 0xffffu));                    \
    arr[7] += bf2f((ushort_t)((v).w >> 16));

// MODE 0: out bf16 [N][128] = mean  ; MODE 1: out f32 [N][128] = uself+bias+mean
template <int MODE>
__global__ __launch_bounds__(256) void gather2_kernel(
    const ushort_t* __restrict__ H,
    const int* __restrict__ rowptr,
    const int* __restrict__ csr_src,
    const float* __restrict__ invdeg,
    const ushort_t* __restrict__ uself,
    const float* __restrict__ bias,
    void* __restrict__ outp,
    int nNodes, int totWaves) {
    int lane = threadIdx.x & 63;
    int wv = blockIdx.x * 4 + (threadIdx.x >> 6);
    int grp = lane >> 4, sub = lane & 15;
    const size_t cofs = (size_t)sub * 8;
    int pair = wv;
    if (pair * 2 >= nNodes) return;
    int r0 = rowptr[pair * 2];
    int r1 = rowptr[pair * 2 + 1];
    int r2 = rowptr[pair * 2 + 2];
    while (true) {
        int npair = pair + totWaves;
        bool hasNext = (npair * 2 < nNodes);
        int n0 = 0, n1 = 0, n2 = 0;
        if (hasNext) {
            n0 = rowptr[npair * 2];
            n1 = rowptr[npair * 2 + 1];
            n2 = rowptr[npair * 2 + 2];
        }
        int nodeA = pair * 2;
        int sA = r0, eA = r1, sB = r1, eB = r2;
        int cA = sA < N_EDGES ? sA : N_EDGES - 1;
        int cB = sB < N_EDGES ? sB : N_EDGES - 1;
        float accA[8] = {}, accB[8] = {};
        for (int ea = sA + grp, eb = sB + grp; ea < eA || eb < eB; ea += 16, eb += 16) {
            bool pa0 = ea < eA, pa1 = ea + 4 < eA, pa2 = ea + 8 < eA, pa3 = ea + 12 < eA;
            bool pb0 = eb < eB, pb1 = eb + 4 < eB, pb2 = eb + 8 < eB, pb3 = eb + 12 < eB;
            int ja0 = pa0 ? ea : cA, ja1 = pa1 ? ea + 4 : cA;
            int ja2 = pa2 ? ea + 8 : cA, ja3 = pa3 ? ea + 12 : cA;
            int jb0 = pb0 ? eb : cB, jb1 = pb1 ? eb + 4 : cB;
            int jb2 = pb2 ? eb + 8 : cB, jb3 = pb3 ? eb + 12 : cB;
            int sa0 = csr_src[ja0], sa1 = csr_src[ja1];
            int sa2 = csr_src[ja2], sa3 = csr_src[ja3];
            int sb0 = csr_src[jb0], sb1 = csr_src[jb1];
            int sb2 = csr_src[jb2], sb3 = csr_src[jb3];
            uint4 va0 = *(const uint4*)(H + (size_t)sa0 * 128 + cofs);
            uint4 va1 = *(const uint4*)(H + (size_t)sa1 * 128 + cofs);
            uint4 va2 = *(const uint4*)(H + (size_t)sa2 * 128 + cofs);
            uint4 va3 = *(const uint4*)(H + (size_t)sa3 * 128 + cofs);
            uint4 vb0 = *(const uint4*)(H + (size_t)sb0 * 128 + cofs);
            uint4 vb1 = *(const uint4*)(H + (size_t)sb1 * 128 + cofs);
            uint4 vb2 = *(const uint4*)(H + (size_t)sb2 * 128 + cofs);
            uint4 vb3 = *(const uint4*)(H + (size_t)sb3 * 128 + cofs);
            if (pa0) { ACC8(accA, va0); }
            if (pa1) { ACC8(accA, va1); }
            if (pa2) { ACC8(accA, va2); }
            if (pa3) { ACC8(accA, va3); }
            if (pb0) { ACC8(accB, vb0); }
            if (pb1) { ACC8(accB, vb1); }
            if (pb2) { ACC8(accB, vb2); }
            if (pb3) { ACC8(accB, vb3); }
        }
#pragma unroll
        for (int j = 0; j < 8; ++j) {
            accA[j] += __shfl_xor(accA[j], 16);
            accA[j] += __shfl_xor(accA[j], 32);
            accB[j] += __shfl_xor(accB[j], 16);
            accB[j] += __shfl_xor(accB[j], 32);
        }
        if (grp == 0) {
            int nodeB = nodeA + 1;
            float scA = invdeg[nodeA];
            float scB = (nodeB < nNodes) ? invdeg[nodeB] : 1.0f;
            if (MODE == 0) {
                uint4 o;
                o.x = (unsigned)f2bf(accA[0] * scA) | ((unsigned)f2bf(accA[1] * scA) << 16);
                o.y = (unsigned)f2bf(accA[2] * scA) | ((unsigned)f2bf(accA[3] * scA) << 16);
                o.z = (unsigned)f2bf(accA[4] * scA) | ((unsigned)f2bf(accA[5] * scA) << 16);
                o.w = (unsigned)f2bf(accA[6] * scA) | ((unsigned)f2bf(accA[7] * scA) << 16);
                *(uint4*)((ushort_t*)outp + (size_t)nodeA * 128 + cofs) = o;
                if (nodeB < nNodes) {
                    uint4 p2;
                    p2.x = (unsigned)f2bf(accB[0] * scB) | ((unsigned)f2bf(accB[1] * scB) << 16);
                    p2.y = (unsigned)f2bf(accB[2] * scB) | ((unsigned)f2bf(accB[3] * scB) << 16);
                    p2.z = (unsigned)f2bf(accB[4] * scB) | ((unsigned)f2bf(accB[5] * scB) << 16);
                    p2.w = (unsigned)f2bf(accB[6] * scB) | ((unsigned)f2bf(accB[7] * scB) << 16);
                    *(uint4*)((ushort_t*)outp + (size_t)nodeB * 128 + cofs) = p2;
                }
            } else {
                uint4 us = *(const uint4*)(uself + (size_t)nodeA * 128 + cofs);
                f32x4 o0, o1;
                o0.x = accA[0] * scA + bf2f((ushort_t)(us.x & 0xffffu)) + bias[cofs + 0];
                o0.y = accA[1] * scA + bf2f((ushort_t)(us.x >> 16)) + bias[cofs + 1];
                o0.z = accA[2] * scA + bf2f((ushort_t)(us.y & 0xffffu)) + bias[cofs + 2];
                o0.w = accA[3] * scA + bf2f((ushort_t)(us.y >> 16)) + bias[cofs + 3];
                o1.x = accA[4] * scA + bf2f((ushort_t)(us.z & 0xffffu)) + bias[cofs + 4];
                o1.y = accA[5] * scA + bf2f((ushort_t)(us.z >> 16)) + bias[cofs + 5];
                o1.z = accA[6] * scA + bf2f((ushort_t)(us.w & 0xffffu)) + bias[cofs + 6];
                o1.w = accA[7] * scA + bf2f((ushort_t)(us.w >> 16)) + bias[cofs + 7];
                float* op = (float*)outp + (size_t)nodeA * 128 + cofs;
                __builtin_nontemporal_store(o0, (f32x4*)op);
                __builtin_nontemporal_store(o1, (f32x4*)(op + 4));
                if (nodeB < nNodes) {
                    uint4 u2 = *(const uint4*)(uself + (size_t)nodeB * 128 + cofs);
                    f32x4 q0, q1;
                    q0.x = accB[0] * scB + bf2f((ushort_t)(u2.x & 0xffffu)) + bias[cofs + 0];
                    q0.y = accB[1] * scB + bf2f((ushort_t)(u2.x >> 16)) + bias[cofs + 1];
                    q0.z = accB[2] * scB + bf2f((ushort_t)(u2.y & 0xffffu)) + bias[cofs + 2];
                    q0.w = accB[3] * scB + bf2f((ushort_t)(u2.y >> 16)) + bias[cofs + 3];
                    q1.x = accB[4] * scB + bf2f((ushort_t)(u2.z & 0xffffu)) + bias[cofs + 4];
                    q1.y = accB[5] * scB + bf2f((ushort_t)(u2.z >> 16)) + bias[cofs + 5];
                    q1.z = accB[6] * scB + bf2f((ushort_t)(u2.w & 0xffffu)) + bias[cofs + 6];
                    q1.w = accB[7] * scB + bf2f((ushort_t)(u2.w >> 16)) + bias[cofs + 7];
                    float* oq = (float*)outp + (size_t)nodeB * 128 + cofs;
                    __builtin_nontemporal_store(q0, (f32x4*)oq);
                    __builtin_nontemporal_store(q1, (f32x4*)(oq + 4));
                }
            }
        }
        if (!hasNext) break;
        pair = npair; r0 = n0; r1 = n1; r2 = n2;
    }
}

// ---------------- fused 2-layer GEMM (h kept in LDS) ------------------------
// Phase 1: h_tile[128][256] = sigmoid([xb|agg] @ Wt1 + b1)  -> LDS (swizzled)
// Phase 2: [uself|uneigh]   = h_tile @ Wt2                  -> global
// 512 threads, 8 waves (2x4 of 64x64). BK=32 double-buffered staging, one
// barrier per K-step (stage(next) issued before MFMAs). 112KB LDS, 1 block/CU.
__global__ __launch_bounds__(512) void gemm_fused_kernel(
    const ushort_t* __restrict__ xb,    // [M][128]
    const ushort_t* __restrict__ agg,   // [M][128]
    const ushort_t* __restrict__ Wt1,   // [256][256] n-major
    const float* __restrict__ b1,
    const ushort_t* __restrict__ Wt2,   // [256][256] n-major
    ushort_t* __restrict__ uself,       // [M][128]
    ushort_t* __restrict__ uneigh,      // [M][128]
    int M) {
    __shared__ ushort_t hs[128 * 256];       // 64KB h tile (row*256 + col^((row&7)<<3))
    __shared__ ushort_t Asb[2][128 * 32];    // 16KB
    __shared__ ushort_t Bsb[2][256 * 32];    // 32KB
    int tid = threadIdx.x;
    int lane = tid & 63, wid = tid >> 6;
    int l15 = lane & 15, kgrp = lane >> 4;
    int bm = blockIdx.x * 128;
    int wr = (wid >> 2) * 64, wc = (wid & 3) * 64;

    auto stageA = [&](int buf, int t) {
        int k0 = t * 32;
        const ushort_t* Ap = (k0 < 128) ? xb : agg;
        int kk0 = k0 & 127;
        int row = wid * 16 + (lane >> 2);
        int scol = ((lane & 3) ^ (row & 3)) << 3;
        int ar = bm + row; if (ar > M - 1) ar = M - 1;
        __builtin_amdgcn_global_load_lds(
            (const GAS void*)(Ap + (size_t)ar * 128 + kk0 + scol),
            (LAS void*)(&Asb[buf][wid * 512]), 16, 0, 0);
    };
    auto stageB = [&](int buf, int t, const ushort_t* Bt) {
        int k0 = t * 32;
#pragma unroll
        for (int t2 = 0; t2 < 2; ++t2) {
            int c = wid * 2 + t2;
            int row = c * 16 + (lane >> 2);
            int scol = ((lane & 3) ^ (row & 3)) << 3;
            __builtin_amdgcn_global_load_lds(
                (const GAS void*)(Bt + (size_t)row * 256 + k0 + scol),
                (LAS void*)(&Bsb[buf][c * 512]), 16, 0, 0);
        }
    };

    f32x4 acc[4][4] = {};

    // ---- phase 1: K over [xb|agg] ----
    stageA(0, 0); stageB(0, 0, Wt1);
    __syncthreads();
#pragma unroll
    for (int t = 0; t < 8; ++t) {
        int buf = t & 1;
        if (t < 7) { stageA(buf ^ 1, t + 1); stageB(buf ^ 1, t + 1, Wt1); }
        bf16x8 af[4], bfv[4];
#pragma unroll
        for (int mi = 0; mi < 4; ++mi) {
            int row = wr + mi * 16 + l15;
            af[mi] = *(const bf16x8*)(&Asb[buf][row * 32 + ((kgrp ^ (row & 3)) << 3)]);
        }
#pragma unroll
        for (int ni = 0; ni < 4; ++ni) {
            int row = wc + ni * 16 + l15;
            bfv[ni] = *(const bf16x8*)(&Bsb[buf][row * 32 + ((kgrp ^ (row & 3)) << 3)]);
        }
#pragma unroll
        for (int mi = 0; mi < 4; ++mi)
#pragma unroll
            for (int ni = 0; ni < 4; ++ni)
                acc[mi][ni] = __builtin_amdgcn_mfma_f32_16x16x32_bf16(
                    af[mi], bfv[ni], acc[mi][ni], 0, 0, 0);
        __syncthreads();
    }

    // ---- phase-1 epilogue: bias+sigmoid -> hs (swizzled), zero acc ----
#pragma unroll
    for (int mi = 0; mi < 4; ++mi) {
#pragma unroll
        for (int ni = 0; ni < 4; ++ni) {
            int hcol = wc + ni * 16 + l15;
            float bv = b1[hcol];
#pragma unroll
            for (int r = 0; r < 4; ++r) {
                float v = acc[mi][ni][r] + bv;
                v = 1.0f / (1.0f + __expf(-v));
                int lr = wr + mi * 16 + kgrp * 4 + r;
                hs[lr * 256 + (hcol ^ ((lr & 7) << 3))] = f2bf(v);
                acc[mi][ni][r] = 0.0f;
            }
        }
    }
    // ---- phase 2: u = h @ Wt2, A from hs ----
    stageB(0, 0, Wt2);
    __syncthreads();  // orders hs writes + drains stage
#pragma unroll
    for (int t = 0; t < 8; ++t) {
        int buf = t & 1;
        if (t < 7) stageB(buf ^ 1, t + 1, Wt2);
        int k0 = t * 32;
        bf16x8 af[4], bfv[4];
#pragma unroll
        for (int mi = 0; mi < 4; ++mi) {
            int row = wr + mi * 16 + l15;
            int c = k0 + kgrp * 8;
            af[mi] = *(const bf16x8*)(&hs[row * 256 + (c ^ ((row & 7) << 3))]);
        }
#pragma unroll
        for (int ni = 0; ni < 4; ++ni) {
            int row = wc + ni * 16 + l15;
            bfv[ni] = *(const bf16x8*)(&Bsb[buf][row * 32 + ((kgrp ^ (row & 3)) << 3)]);
        }
#pragma unroll
        for (int mi = 0; mi < 4; ++mi)
#pragma unroll
            for (int ni = 0; ni < 4; ++ni)
                acc[mi][ni] = __builtin_amdgcn_mfma_f32_16x16x32_bf16(
                    af[mi], bfv[ni], acc[mi][ni], 0, 0, 0);
        __syncthreads();
    }

    // ---- final epilogue: per-wave per-mi 16x64 transpose slabs, dual store --
    ushort_t* my = ((ushort_t*)Asb) + wid * 1024;
#pragma unroll
    for (int mi = 0; mi < 4; ++mi) {
#pragma unroll
        for (int ni = 0; ni < 4; ++ni) {
#pragma unroll
            for (int r = 0; r < 4; ++r) {
                int lr = kgrp * 4 + r;
                int lc = (ni * 16 + l15) ^ (kgrp << 3);
                my[lr * 64 + lc] = f2bf(acc[mi][ni][r]);
            }
        }
#pragma unroll
        for (int it = 0; it < 2; ++it) {
            int r2 = (lane >> 3) + it * 8;
            int swz = ((r2 >> 2) & 3) << 3;
            int c2 = ((lane & 7) << 3) ^ swz;
            bf16x8 vv = *(const bf16x8*)(&my[r2 * 64 + c2]);
            int grow = bm + wr + mi * 16 + r2;
            if (grow < M) {
                int gc = wc + (c2 ^ swz);
                ushort_t* dstp = (gc < 128)
                    ? uself + (size_t)grow * 128 + gc
                    : uneigh + (size_t)grow * 128 + (gc - 128);
                *(bf16x8*)dstp = vv;
            }
        }
    }
}

extern "C" void kernel_launch(void* const* d_in, const int* in_sizes, int n_in,
                              void* d_out, int out_size, void* d_ws, size_t ws_size,
                              hipStream_t stream) {
    const float* x        = (const float*)d_in[0];
    const int*   src      = (const int*)d_in[1];
    const int*   dst      = (const int*)d_in[2];
    const float* W_self1  = (const float*)d_in[3];
    const float* W_neigh1 = (const float*)d_in[4];
    const float* b1       = (const float*)d_in[5];
    const float* W_self2  = (const float*)d_in[6];
    const float* W_neigh2 = (const float*)d_in[7];
    const float* b2       = (const float*)d_in[8];
    float* out = (float*)d_out;

    // ---- workspace layout ----
    char* p = (char*)d_ws;
    auto alloc = [&](size_t bytes) { char* r = p; p += (bytes + 255) & ~(size_t)255; return r; };
    float*    invdeg   = (float*)alloc((size_t)N_NODES * 4);
    ushort_t* xb       = (ushort_t*)alloc((size_t)N_NODES * 128 * 2);
    ushort_t* agg      = (ushort_t*)alloc((size_t)N_NODES * 128 * 2);
    ushort_t* uself    = (ushort_t*)alloc((size_t)N_NODES * 128 * 2);
    ushort_t* uneigh   = (ushort_t*)alloc((size_t)N_NODES * 128 * 2);
    ushort_t* Wt1      = (ushort_t*)alloc((size_t)256 * 256 * 2);
    ushort_t* Wt2      = (ushort_t*)alloc((size_t)256 * 256 * 2);
    int* rowptr        = (int*)alloc((size_t)(N_NODES + 1) * 4);
    int* bucket_cnt    = (int*)alloc((size_t)NBUCK * 4);
    int* bbase         = (int*)alloc((size_t)(NBUCK + 1) * 4);
    int* bcursor       = (int*)alloc((size_t)NBUCK * 4);
    unsigned int* pairs= (unsigned int*)alloc((size_t)N_EDGES * 4);
    int* csr_src       = (int*)alloc((size_t)N_EDGES * 4);

    // ---- converts ----
    convert_x_kernel<<<(N_NODES * F_IN / 4 + 255) / 256, 256, 0, stream>>>(
        x, xb, N_NODES * F_IN / 4);
    wtransK_kernel<<<(256 * 256 + 255) / 256, 256, 0, stream>>>(
        W_self1, W_neigh1, Wt1, 128, 256, 256);
    wtransN_kernel<<<(256 * 256 + 255) / 256, 256, 0, stream>>>(
        W_self2, W_neigh2, Wt2, 256, 128);

    // ---- CSR build ----
    hipMemsetAsync(bucket_cnt, 0, (size_t)NBUCK * sizeof(int), stream);
    bucket_count_kernel<<<(N_EDGES + CHUNK - 1) / CHUNK, 256, 0, stream>>>(
        dst, bucket_cnt, N_EDGES);
    bucket_scan_kernel<<<1, 512, 0, stream>>>(bucket_cnt, bbase, bcursor, rowptr);
    bin_edges_kernel<<<(N_EDGES + CHUNK - 1) / CHUNK, 256, 0, stream>>>(
        src, dst, bcursor, pairs, N_EDGES);
    sort_bucket_kernel<<<NBUCK, 256, 0, stream>>>(
        pairs, bbase, rowptr, invdeg, csr_src, N_NODES);

    const int GATHER_BLOCKS = 2048;
    const int TOT_WAVES = GATHER_BLOCKS * 4;

    // ---- layer 1 gather, then fused 2-layer GEMM, then final gather ----
    gather2_kernel<0><<<GATHER_BLOCKS, 256, 0, stream>>>(
        xb, rowptr, csr_src, invdeg, nullptr, nullptr, agg, N_NODES, TOT_WAVES);
    {
        dim3 grid((N_NODES + 127) / 128);
        gemm_fused_kernel<<<grid, 512, 0, stream>>>(
            xb, agg, Wt1, b1, Wt2, uself, uneigh, N_NODES);
    }
    gather2_kernel<1><<<GATHER_BLOCKS, 256, 0, stream>>>(
        uneigh, rowptr, csr_src, invdeg, uself, b2, out, N_NODES, TOT_WAVES);
}

// Round 16
// 273.471 us; speedup vs baseline: 1.0567x; 1.0567x over previous
//
#include <hip/hip_runtime.h>
#include <hip/hip_bf16.h>

#define N_NODES 100000
#define N_EDGES 1600000
#define F_IN 128
#define F_HID 256
#define F_OUT 128

typedef unsigned short ushort_t;
typedef __attribute__((ext_vector_type(4))) float f32x4;
typedef __attribute__((ext_vector_type(8))) short bf16x8;

#define GAS __attribute__((address_space(1)))
#define LAS __attribute__((address_space(3)))

__device__ __forceinline__ float bf2f(ushort_t u) {
    unsigned int x = ((unsigned int)u) << 16;
    return __builtin_bit_cast(float, x);
}
__device__ __forceinline__ ushort_t f2bf(float f) {
    unsigned int x = __builtin_bit_cast(unsigned int, f);
    unsigned int r = (x + 0x7fffu + ((x >> 16) & 1u)) >> 16;
    return (ushort_t)r;
}

// ---------------- bucket-sort CSR build (round-11, unchanged) ----------------
#define NBUCK ((N_NODES + 255) >> 8)  // 391
#define CHUNK 4096

__global__ __launch_bounds__(256) void bucket_count_kernel(
    const int* __restrict__ dst, int* __restrict__ bucket_cnt, int n) {
    __shared__ int hist[NBUCK];
    int tid = threadIdx.x;
    int e0 = blockIdx.x * CHUNK;
    int cnt = n - e0; if (cnt > CHUNK) cnt = CHUNK;
    for (int b = tid; b < NBUCK; b += 256) hist[b] = 0;
    __syncthreads();
    for (int i = tid; i < cnt; i += 256) {
        int d = __builtin_nontemporal_load(dst + e0 + i);
        atomicAdd(&hist[d >> 8], 1);
    }
    __syncthreads();
    for (int b = tid; b < NBUCK; b += 256)
        if (hist[b]) atomicAdd(&bucket_cnt[b], hist[b]);
}

__global__ __launch_bounds__(512) void bucket_scan_kernel(
    const int* __restrict__ bucket_cnt, int* __restrict__ bbase,
    int* __restrict__ bcursor, int* __restrict__ rowptr) {
    __shared__ int tmp[512];
    int tid = threadIdx.x;
    int v = (tid < NBUCK) ? bucket_cnt[tid] : 0;
    tmp[tid] = v;
    __syncthreads();
#pragma unroll
    for (int off = 1; off < 512; off <<= 1) {
        int t = (tid >= off) ? tmp[tid - off] : 0;
        __syncthreads();
        tmp[tid] += t;
        __syncthreads();
    }
    if (tid < NBUCK) {
        int base = tmp[tid] - v;
        bbase[tid] = base;
        bcursor[tid] = base;
    }
    if (tid == 0) {
        bbase[NBUCK] = N_EDGES;
        rowptr[N_NODES] = N_EDGES;
    }
}

__global__ __launch_bounds__(256) void bin_edges_kernel(
    const int* __restrict__ src, const int* __restrict__ dst,
    int* __restrict__ bcursor, unsigned int* __restrict__ pairs, int n) {
    __shared__ int sdst[CHUNK];
    __shared__ int ssrc[CHUNK];
    __shared__ int hist[NBUCK];
    __shared__ int resv[NBUCK];
    int tid = threadIdx.x;
    int e0 = blockIdx.x * CHUNK;
    int cnt = n - e0; if (cnt > CHUNK) cnt = CHUNK;
    for (int b = tid; b < NBUCK; b += 256) hist[b] = 0;
    __syncthreads();
    for (int i = tid; i < cnt; i += 256) {
        int d = __builtin_nontemporal_load(dst + e0 + i);
        int s = __builtin_nontemporal_load(src + e0 + i);
        sdst[i] = d;
        ssrc[i] = s;
        atomicAdd(&hist[d >> 8], 1);
    }
    __syncthreads();
    for (int b = tid; b < NBUCK; b += 256) {
        int h = hist[b];
        resv[b] = h ? atomicAdd(&bcursor[b], h) : 0;
        hist[b] = 0;
    }
    __syncthreads();
    for (int i = tid; i < cnt; i += 256) {
        int d = sdst[i], s = ssrc[i];
        int b = d >> 8;
        int off = atomicAdd(&hist[b], 1);
        pairs[resv[b] + off] = ((unsigned)(d & 255) << 17) | (unsigned)s;
    }
}

__global__ __launch_bounds__(256) void sort_bucket_kernel(
    const unsigned int* __restrict__ pairs, const int* __restrict__ bbase,
    int* __restrict__ rowptr, float* __restrict__ invdeg,
    int* __restrict__ csr_src, int nNodes) {
    __shared__ int lcnt[256];
    __shared__ int lrp[256];
    int tid = threadIdx.x;
    int base = blockIdx.x << 8;
    int nn = nNodes - base; if (nn > 256) nn = 256;
    lcnt[tid] = 0;
    __syncthreads();
    int e0 = bbase[blockIdx.x], e1 = bbase[blockIdx.x + 1];
    for (int i = e0 + tid; i < e1; i += 256)
        atomicAdd(&lcnt[pairs[i] >> 17], 1);
    __syncthreads();
    int v = lcnt[tid];
    lrp[tid] = v;
    __syncthreads();
#pragma unroll
    for (int off = 1; off < 256; off <<= 1) {
        int t = (tid >= off) ? lrp[tid - off] : 0;
        __syncthreads();
        lrp[tid] += t;
        __syncthreads();
    }
    lcnt[tid] = 0;
    lrp[tid] = lrp[tid] - v + e0;
    if (tid < nn) {
        rowptr[base + tid] = lrp[tid];
        invdeg[base + tid] = 1.0f / fmaxf((float)v, 1.0f);
    }
    __syncthreads();
    for (int i = e0 + tid; i < e1; i += 256) {
        unsigned pv = pairs[i];
        int j = (int)(pv >> 17);
        int off = atomicAdd(&lcnt[j], 1);
        csr_src[lrp[j] + off] = (int)(pv & 0x1FFFFu);
    }
}

// ---------------- fp32 -> bf16 converts ----------------
__global__ __launch_bounds__(256) void convert_x_kernel(const float* __restrict__ x,
                                                        ushort_t* __restrict__ xb, int n4) {
    int i = blockIdx.x * 256 + threadIdx.x;
    if (i >= n4) return;
    int e = i * 4;
    f32x4 v = __builtin_nontemporal_load((const f32x4*)(x + e));
    ushort4 o;
    o.x = f2bf(v.x); o.y = f2bf(v.y); o.z = f2bf(v.z); o.w = f2bf(v.w);
    *(ushort4*)(xb + e) = o;
}

__global__ __launch_bounds__(256) void wtransK_kernel(const float* __restrict__ W1,
                                                      const float* __restrict__ W2,
                                                      ushort_t* __restrict__ Wt,
                                                      int Kx, int Ktot, int N) {
    int i = blockIdx.x * 256 + threadIdx.x;
    if (i >= N * Ktot) return;
    int n = i / Ktot, k = i - n * Ktot;
    float v = (k < Kx) ? W1[(size_t)k * N + n] : W2[(size_t)(k - Kx) * N + n];
    Wt[(size_t)n * Ktot + k] = f2bf(v);
}

__global__ __launch_bounds__(256) void wtransN_kernel(const float* __restrict__ Wa,
                                                      const float* __restrict__ Wb,
                                                      ushort_t* __restrict__ Wt,
                                                      int K, int Nh) {
    int i = blockIdx.x * 256 + threadIdx.x;
    if (i >= 2 * Nh * K) return;
    int n = i / K, k = i - n * K;
    const float* W = (n < Nh) ? Wa : Wb;
    int nn = (n < Nh) ? n : n - Nh;
    Wt[(size_t)n * K + k] = f2bf(W[(size_t)k * Nh + nn]);
}

// ---------------- persistent dual-node gather (round-12, unchanged) ---------
#define ACC8(arr, v)                                                \
    arr[0] += bf2f((ushort_t)((v).x & 0xffffu));                    \
    arr[1] += bf2f((ushort_t)((v).x >> 16));                        \
    arr[2] += bf2f((ushort_t)((v).y & 0xffffu));                    \
    arr[3] += bf2f((ushort_t)((v).y >> 16));                        \
    arr[4] += bf2f((ushort_t)((v).z & 0xffffu));                    \
    arr[5] += bf2f((ushort_t)((v).z >> 16));                        \
    arr[6] += bf2f((ushort_t)((v).w & 0xffffu));                    \
    arr[7] += bf2f((ushort_t)((v).w >> 16));

// MODE 0: out bf16 [N][128] = mean  ; MODE 1: out f32 [N][128] = uself+bias+mean
template <int MODE>
__global__ __launch_bounds__(256) void gather2_kernel(
    const ushort_t* __restrict__ H,
    const int* __restrict__ rowptr,
    const int* __restrict__ csr_src,
    const float* __restrict__ invdeg,
    const ushort_t* __restrict__ uself,
    const float* __restrict__ bias,
    void* __restrict__ outp,
    int nNodes, int totWaves) {
    int lane = threadIdx.x & 63;
    int wv = blockIdx.x * 4 + (threadIdx.x >> 6);
    int grp = lane >> 4, sub = lane & 15;
    const size_t cofs = (size_t)sub * 8;
    int pair = wv;
    if (pair * 2 >= nNodes) return;
    int r0 = rowptr[pair * 2];
    int r1 = rowptr[pair * 2 + 1];
    int r2 = rowptr[pair * 2 + 2];
    while (true) {
        int npair = pair + totWaves;
        bool hasNext = (npair * 2 < nNodes);
        int n0 = 0, n1 = 0, n2 = 0;
        if (hasNext) {
            n0 = rowptr[npair * 2];
            n1 = rowptr[npair * 2 + 1];
            n2 = rowptr[npair * 2 + 2];
        }
        int nodeA = pair * 2;
        int sA = r0, eA = r1, sB = r1, eB = r2;
        int cA = sA < N_EDGES ? sA : N_EDGES - 1;
        int cB = sB < N_EDGES ? sB : N_EDGES - 1;
        float accA[8] = {}, accB[8] = {};
        for (int ea = sA + grp, eb = sB + grp; ea < eA || eb < eB; ea += 16, eb += 16) {
            bool pa0 = ea < eA, pa1 = ea + 4 < eA, pa2 = ea + 8 < eA, pa3 = ea + 12 < eA;
            bool pb0 = eb < eB, pb1 = eb + 4 < eB, pb2 = eb + 8 < eB, pb3 = eb + 12 < eB;
            int ja0 = pa0 ? ea : cA, ja1 = pa1 ? ea + 4 : cA;
            int ja2 = pa2 ? ea + 8 : cA, ja3 = pa3 ? ea + 12 : cA;
            int jb0 = pb0 ? eb : cB, jb1 = pb1 ? eb + 4 : cB;
            int jb2 = pb2 ? eb + 8 : cB, jb3 = pb3 ? eb + 12 : cB;
            int sa0 = csr_src[ja0], sa1 = csr_src[ja1];
            int sa2 = csr_src[ja2], sa3 = csr_src[ja3];
            int sb0 = csr_src[jb0], sb1 = csr_src[jb1];
            int sb2 = csr_src[jb2], sb3 = csr_src[jb3];
            uint4 va0 = *(const uint4*)(H + (size_t)sa0 * 128 + cofs);
            uint4 va1 = *(const uint4*)(H + (size_t)sa1 * 128 + cofs);
            uint4 va2 = *(const uint4*)(H + (size_t)sa2 * 128 + cofs);
            uint4 va3 = *(const uint4*)(H + (size_t)sa3 * 128 + cofs);
            uint4 vb0 = *(const uint4*)(H + (size_t)sb0 * 128 + cofs);
            uint4 vb1 = *(const uint4*)(H + (size_t)sb1 * 128 + cofs);
            uint4 vb2 = *(const uint4*)(H + (size_t)sb2 * 128 + cofs);
            uint4 vb3 = *(const uint4*)(H + (size_t)sb3 * 128 + cofs);
            if (pa0) { ACC8(accA, va0); }
            if (pa1) { ACC8(accA, va1); }
            if (pa2) { ACC8(accA, va2); }
            if (pa3) { ACC8(accA, va3); }
            if (pb0) { ACC8(accB, vb0); }
            if (pb1) { ACC8(accB, vb1); }
            if (pb2) { ACC8(accB, vb2); }
            if (pb3) { ACC8(accB, vb3); }
        }
#pragma unroll
        for (int j = 0; j < 8; ++j) {
            accA[j] += __shfl_xor(accA[j], 16);
            accA[j] += __shfl_xor(accA[j], 32);
            accB[j] += __shfl_xor(accB[j], 16);
            accB[j] += __shfl_xor(accB[j], 32);
        }
        if (grp == 0) {
            int nodeB = nodeA + 1;
            float scA = invdeg[nodeA];
            float scB = (nodeB < nNodes) ? invdeg[nodeB] : 1.0f;
            if (MODE == 0) {
                uint4 o;
                o.x = (unsigned)f2bf(accA[0] * scA) | ((unsigned)f2bf(accA[1] * scA) << 16);
                o.y = (unsigned)f2bf(accA[2] * scA) | ((unsigned)f2bf(accA[3] * scA) << 16);
                o.z = (unsigned)f2bf(accA[4] * scA) | ((unsigned)f2bf(accA[5] * scA) << 16);
                o.w = (unsigned)f2bf(accA[6] * scA) | ((unsigned)f2bf(accA[7] * scA) << 16);
                *(uint4*)((ushort_t*)outp + (size_t)nodeA * 128 + cofs) = o;
                if (nodeB < nNodes) {
                    uint4 p2;
                    p2.x = (unsigned)f2bf(accB[0] * scB) | ((unsigned)f2bf(accB[1] * scB) << 16);
                    p2.y = (unsigned)f2bf(accB[2] * scB) | ((unsigned)f2bf(accB[3] * scB) << 16);
                    p2.z = (unsigned)f2bf(accB[4] * scB) | ((unsigned)f2bf(accB[5] * scB) << 16);
                    p2.w = (unsigned)f2bf(accB[6] * scB) | ((unsigned)f2bf(accB[7] * scB) << 16);
                    *(uint4*)((ushort_t*)outp + (size_t)nodeB * 128 + cofs) = p2;
                }
            } else {
                uint4 us = *(const uint4*)(uself + (size_t)nodeA * 128 + cofs);
                f32x4 o0, o1;
                o0.x = accA[0] * scA + bf2f((ushort_t)(us.x & 0xffffu)) + bias[cofs + 0];
                o0.y = accA[1] * scA + bf2f((ushort_t)(us.x >> 16)) + bias[cofs + 1];
                o0.z = accA[2] * scA + bf2f((ushort_t)(us.y & 0xffffu)) + bias[cofs + 2];
                o0.w = accA[3] * scA + bf2f((ushort_t)(us.y >> 16)) + bias[cofs + 3];
                o1.x = accA[4] * scA + bf2f((ushort_t)(us.z & 0xffffu)) + bias[cofs + 4];
                o1.y = accA[5] * scA + bf2f((ushort_t)(us.z >> 16)) + bias[cofs + 5];
                o1.z = accA[6] * scA + bf2f((ushort_t)(us.w & 0xffffu)) + bias[cofs + 6];
                o1.w = accA[7] * scA + bf2f((ushort_t)(us.w >> 16)) + bias[cofs + 7];
                float* op = (float*)outp + (size_t)nodeA * 128 + cofs;
                __builtin_nontemporal_store(o0, (f32x4*)op);
                __builtin_nontemporal_store(o1, (f32x4*)(op + 4));
                if (nodeB < nNodes) {
                    uint4 u2 = *(const uint4*)(uself + (size_t)nodeB * 128 + cofs);
                    f32x4 q0, q1;
                    q0.x = accB[0] * scB + bf2f((ushort_t)(u2.x & 0xffffu)) + bias[cofs + 0];
                    q0.y = accB[1] * scB + bf2f((ushort_t)(u2.x >> 16)) + bias[cofs + 1];
                    q0.z = accB[2] * scB + bf2f((ushort_t)(u2.y & 0xffffu)) + bias[cofs + 2];
                    q0.w = accB[3] * scB + bf2f((ushort_t)(u2.y >> 16)) + bias[cofs + 3];
                    q1.x = accB[4] * scB + bf2f((ushort_t)(u2.z & 0xffffu)) + bias[cofs + 4];
                    q1.y = accB[5] * scB + bf2f((ushort_t)(u2.z >> 16)) + bias[cofs + 5];
                    q1.z = accB[6] * scB + bf2f((ushort_t)(u2.w & 0xffffu)) + bias[cofs + 6];
                    q1.w = accB[7] * scB + bf2f((ushort_t)(u2.w >> 16)) + bias[cofs + 7];
                    float* oq = (float*)outp + (size_t)nodeB * 128 + cofs;
                    __builtin_nontemporal_store(q0, (f32x4*)oq);
                    __builtin_nontemporal_store(q1, (f32x4*)(oq + 4));
                }
            }
        }
        if (!hasNext) break;
        pair = npair; r0 = n0; r1 = n1; r2 = n2;
    }
}

// ---------------- fused 2-layer GEMM, BM=64 (2 blocks/CU) -------------------
// Phase 1: h_tile[64][256] = sigmoid([xb|agg] @ Wt1 + b1)  -> LDS (swizzled)
// Phase 2: [uself|uneigh]  = h_tile @ Wt2                  -> global
// 512 threads, 8 waves (2x4 of 32x64). BK=32 double-buffered, stage(next)
// before MFMAs, one barrier per step. LDS 72KB -> 2 blocks/CU (16 waves).
// FIX vs round-15: epilogue scratch moved from Asb (8KB, overflowed for
// waves 4-7 -> OOB LDS writes, absmax 1.46) to hs (32KB, dead after phase 2).
__global__ __launch_bounds__(512) void gemm_fused_kernel(
    const ushort_t* __restrict__ xb,    // [M][128]
    const ushort_t* __restrict__ agg,   // [M][128]
    const ushort_t* __restrict__ Wt1,   // [256][256] n-major
    const float* __restrict__ b1,
    const ushort_t* __restrict__ Wt2,   // [256][256] n-major
    ushort_t* __restrict__ uself,       // [M][128]
    ushort_t* __restrict__ uneigh,      // [M][128]
    int M) {
    __shared__ ushort_t hs[64 * 256];        // 32KB (row*256 + col^((row&7)<<3))
    __shared__ ushort_t Asb[2][64 * 32];     // 8KB
    __shared__ ushort_t Bsb[2][256 * 32];    // 32KB
    int tid = threadIdx.x;
    int lane = tid & 63, wid = tid >> 6;
    int l15 = lane & 15, kgrp = lane >> 4;
    int bm = blockIdx.x * 64;
    int wr = (wid >> 2) * 32, wc = (wid & 3) * 64;

    auto stageA = [&](int buf, int t) {
        if (wid >= 4) return;                 // 64 rows = 4 wave-chunks
        int k0 = t * 32;
        const ushort_t* Ap = (k0 < 128) ? xb : agg;
        int kk0 = k0 & 127;
        int row = wid * 16 + (lane >> 2);
        int scol = ((lane & 3) ^ (row & 3)) << 3;
        int ar = bm + row; if (ar > M - 1) ar = M - 1;
        __builtin_amdgcn_global_load_lds(
            (const GAS void*)(Ap + (size_t)ar * 128 + kk0 + scol),
            (LAS void*)(&Asb[buf][wid * 512]), 16, 0, 0);
    };
    auto stageB = [&](int buf, int t, const ushort_t* Bt) {
        int k0 = t * 32;
#pragma unroll
        for (int t2 = 0; t2 < 2; ++t2) {
            int c = wid * 2 + t2;
            int row = c * 16 + (lane >> 2);
            int scol = ((lane & 3) ^ (row & 3)) << 3;
            __builtin_amdgcn_global_load_lds(
                (const GAS void*)(Bt + (size_t)row * 256 + k0 + scol),
                (LAS void*)(&Bsb[buf][c * 512]), 16, 0, 0);
        }
    };

    f32x4 acc[2][4] = {};

    // ---- phase 1: K over [xb|agg] ----
    stageA(0, 0); stageB(0, 0, Wt1);
    __syncthreads();
#pragma unroll
    for (int t = 0; t < 8; ++t) {
        int buf = t & 1;
        if (t < 7) { stageA(buf ^ 1, t + 1); stageB(buf ^ 1, t + 1, Wt1); }
        bf16x8 af[2], bfv[4];
#pragma unroll
        for (int mi = 0; mi < 2; ++mi) {
            int row = wr + mi * 16 + l15;
            af[mi] = *(const bf16x8*)(&Asb[buf][row * 32 + ((kgrp ^ (row & 3)) << 3)]);
        }
#pragma unroll
        for (int ni = 0; ni < 4; ++ni) {
            int row = wc + ni * 16 + l15;
            bfv[ni] = *(const bf16x8*)(&Bsb[buf][row * 32 + ((kgrp ^ (row & 3)) << 3)]);
        }
#pragma unroll
        for (int mi = 0; mi < 2; ++mi)
#pragma unroll
            for (int ni = 0; ni < 4; ++ni)
                acc[mi][ni] = __builtin_amdgcn_mfma_f32_16x16x32_bf16(
                    af[mi], bfv[ni], acc[mi][ni], 0, 0, 0);
        __syncthreads();
    }

    // ---- phase-1 epilogue: bias+sigmoid -> hs (swizzled), zero acc ----
#pragma unroll
    for (int mi = 0; mi < 2; ++mi) {
#pragma unroll
        for (int ni = 0; ni < 4; ++ni) {
            int hcol = wc + ni * 16 + l15;
            float bv = b1[hcol];
#pragma unroll
            for (int r = 0; r < 4; ++r) {
                float v = acc[mi][ni][r] + bv;
                v = 1.0f / (1.0f + __expf(-v));
                int lr = wr + mi * 16 + kgrp * 4 + r;
                hs[lr * 256 + (hcol ^ ((lr & 7) << 3))] = f2bf(v);
                acc[mi][ni][r] = 0.0f;
            }
        }
    }
    // ---- phase 2: u = h @ Wt2, A from hs ----
    stageB(0, 0, Wt2);
    __syncthreads();  // orders hs writes + drains stage
#pragma unroll
    for (int t = 0; t < 8; ++t) {
        int buf = t & 1;
        if (t < 7) stageB(buf ^ 1, t + 1, Wt2);
        int k0 = t * 32;
        bf16x8 af[2], bfv[4];
#pragma unroll
        for (int mi = 0; mi < 2; ++mi) {
            int row = wr + mi * 16 + l15;
            int c = k0 + kgrp * 8;
            af[mi] = *(const bf16x8*)(&hs[row * 256 + (c ^ ((row & 7) << 3))]);
        }
#pragma unroll
        for (int ni = 0; ni < 4; ++ni) {
            int row = wc + ni * 16 + l15;
            bfv[ni] = *(const bf16x8*)(&Bsb[buf][row * 32 + ((kgrp ^ (row & 3)) << 3)]);
        }
#pragma unroll
        for (int mi = 0; mi < 2; ++mi)
#pragma unroll
            for (int ni = 0; ni < 4; ++ni)
                acc[mi][ni] = __builtin_amdgcn_mfma_f32_16x16x32_bf16(
                    af[mi], bfv[ni], acc[mi][ni], 0, 0, 0);
        __syncthreads();
    }

    // ---- final epilogue: per-wave per-mi 16x64 transpose slabs, dual store --
    // scratch in hs (dead after phase 2; 8 waves x 1024 = 8K of 16K elems)
    ushort_t* my = hs + wid * 1024;
#pragma unroll
    for (int mi = 0; mi < 2; ++mi) {
#pragma unroll
        for (int ni = 0; ni < 4; ++ni) {
#pragma unroll
            for (int r = 0; r < 4; ++r) {
                int lr = kgrp * 4 + r;
                int lc = (ni * 16 + l15) ^ (kgrp << 3);
                my[lr * 64 + lc] = f2bf(acc[mi][ni][r]);
            }
        }
#pragma unroll
        for (int it = 0; it < 2; ++it) {
            int r2 = (lane >> 3) + it * 8;
            int swz = ((r2 >> 2) & 3) << 3;
            int c2 = ((lane & 7) << 3) ^ swz;
            bf16x8 vv = *(const bf16x8*)(&my[r2 * 64 + c2]);
            int grow = bm + wr + mi * 16 + r2;
            if (grow < M) {
                int gc = wc + (c2 ^ swz);
                ushort_t* dstp = (gc < 128)
                    ? uself + (size_t)grow * 128 + gc
                    : uneigh + (size_t)grow * 128 + (gc - 128);
                *(bf16x8*)dstp = vv;
            }
        }
    }
}

extern "C" void kernel_launch(void* const* d_in, const int* in_sizes, int n_in,
                              void* d_out, int out_size, void* d_ws, size_t ws_size,
                              hipStream_t stream) {
    const float* x        = (const float*)d_in[0];
    const int*   src      = (const int*)d_in[1];
    const int*   dst      = (const int*)d_in[2];
    const float* W_self1  = (const float*)d_in[3];
    const float* W_neigh1 = (const float*)d_in[4];
    const float* b1       = (const float*)d_in[5];
    const float* W_self2  = (const float*)d_in[6];
    const float* W_neigh2 = (const float*)d_in[7];
    const float* b2       = (const float*)d_in[8];
    float* out = (float*)d_out;

    // ---- workspace layout ----
    char* p = (char*)d_ws;
    auto alloc = [&](size_t bytes) { char* r = p; p += (bytes + 255) & ~(size_t)255; return r; };
    float*    invdeg   = (float*)alloc((size_t)N_NODES * 4);
    ushort_t* xb       = (ushort_t*)alloc((size_t)N_NODES * 128 * 2);
    ushort_t* agg      = (ushort_t*)alloc((size_t)N_NODES * 128 * 2);
    ushort_t* uself    = (ushort_t*)alloc((size_t)N_NODES * 128 * 2);
    ushort_t* uneigh   = (ushort_t*)alloc((size_t)N_NODES * 128 * 2);
    ushort_t* Wt1      = (ushort_t*)alloc((size_t)256 * 256 * 2);
    ushort_t* Wt2      = (ushort_t*)alloc((size_t)256 * 256 * 2);
    int* rowptr        = (int*)alloc((size_t)(N_NODES + 1) * 4);
    int* bucket_cnt    = (int*)alloc((size_t)NBUCK * 4);
    int* bbase         = (int*)alloc((size_t)(NBUCK + 1) * 4);
    int* bcursor       = (int*)alloc((size_t)NBUCK * 4);
    unsigned int* pairs= (unsigned int*)alloc((size_t)N_EDGES * 4);
    int* csr_src       = (int*)alloc((size_t)N_EDGES * 4);

    // ---- converts ----
    convert_x_kernel<<<(N_NODES * F_IN / 4 + 255) / 256, 256, 0, stream>>>(
        x, xb, N_NODES * F_IN / 4);
    wtransK_kernel<<<(256 * 256 + 255) / 256, 256, 0, stream>>>(
        W_self1, W_neigh1, Wt1, 128, 256, 256);
    wtransN_kernel<<<(256 * 256 + 255) / 256, 256, 0, stream>>>(
        W_self2, W_neigh2, Wt2, 256, 128);

    // ---- CSR build ----
    hipMemsetAsync(bucket_cnt, 0, (size_t)NBUCK * sizeof(int), stream);
    bucket_count_kernel<<<(N_EDGES + CHUNK - 1) / CHUNK, 256, 0, stream>>>(
        dst, bucket_cnt, N_EDGES);
    bucket_scan_kernel<<<1, 512, 0, stream>>>(bucket_cnt, bbase, bcursor, rowptr);
    bin_edges_kernel<<<(N_EDGES + CHUNK - 1) / CHUNK, 256, 0, stream>>>(
        src, dst, bcursor, pairs, N_EDGES);
    sort_bucket_kernel<<<NBUCK, 256, 0, stream>>>(
        pairs, bbase, rowptr, invdeg, csr_src, N_NODES);

    const int GATHER_BLOCKS = 2048;
    const int TOT_WAVES = GATHER_BLOCKS * 4;

    // ---- layer 1 gather, then fused 2-layer GEMM, then final gather ----
    gather2_kernel<0><<<GATHER_BLOCKS, 256, 0, stream>>>(
        xb, rowptr, csr_src, invdeg, nullptr, nullptr, agg, N_NODES, TOT_WAVES);
    {
        dim3 grid((N_NODES + 63) / 64);
        gemm_fused_kernel<<<grid, 512, 0, stream>>>(
            xb, agg, Wt1, b1, Wt2, uself, uneigh, N_NODES);
    }
    gather2_kernel<1><<<GATHER_BLOCKS, 256, 0, stream>>>(
        uneigh, rowptr, csr_src, invdeg, uself, b2, out, N_NODES, TOT_WAVES);
}

// Round 17
// 255.142 us; speedup vs baseline: 1.1326x; 1.0718x over previous
//
#include <hip/hip_runtime.h>
#include <hip/hip_bf16.h>

#define N_NODES 100000
#define N_EDGES 1600000
#define F_IN 128
#define F_HID 256
#define F_OUT 128

typedef unsigned short ushort_t;
typedef __attribute__((ext_vector_type(4))) float f32x4;
typedef __attribute__((ext_vector_type(8))) short bf16x8;

#define GAS __attribute__((address_space(1)))
#define LAS __attribute__((address_space(3)))

__device__ __forceinline__ float bf2f(ushort_t u) {
    unsigned int x = ((unsigned int)u) << 16;
    return __builtin_bit_cast(float, x);
}
__device__ __forceinline__ ushort_t f2bf(float f) {
    unsigned int x = __builtin_bit_cast(unsigned int, f);
    unsigned int r = (x + 0x7fffu + ((x >> 16) & 1u)) >> 16;
    return (ushort_t)r;
}

// ---------------- padded-bucket CSR build (no count/scan passes) ------------
// Bucket = 256 consecutive dst nodes, fixed capacity CAP edges at b*CAP in
// pairs/csr_src (mean 4096, +64 sigma safe). bin_edges reserves via bcursor
// (zero-init); sort_bucket derives per-node (start,end) itself -> rowse int2.
#define NBUCK ((N_NODES + 255) >> 8)  // 391
#define CHUNK 4096
#define BCAP 8192

__global__ __launch_bounds__(256) void bin_edges_kernel(
    const int* __restrict__ src, const int* __restrict__ dst,
    int* __restrict__ bcursor, unsigned int* __restrict__ pairs, int n) {
    __shared__ int sdst[CHUNK];
    __shared__ int ssrc[CHUNK];
    __shared__ int hist[NBUCK];
    __shared__ int resv[NBUCK];
    int tid = threadIdx.x;
    int e0 = blockIdx.x * CHUNK;
    int cnt = n - e0; if (cnt > CHUNK) cnt = CHUNK;
    for (int b = tid; b < NBUCK; b += 256) hist[b] = 0;
    __syncthreads();
    for (int i = tid; i < cnt; i += 256) {
        int d = __builtin_nontemporal_load(dst + e0 + i);
        int s = __builtin_nontemporal_load(src + e0 + i);
        sdst[i] = d;
        ssrc[i] = s;
        atomicAdd(&hist[d >> 8], 1);
    }
    __syncthreads();
    for (int b = tid; b < NBUCK; b += 256) {
        int h = hist[b];
        resv[b] = h ? (b * BCAP + atomicAdd(&bcursor[b], h)) : 0;
        hist[b] = 0;
    }
    __syncthreads();
    for (int i = tid; i < cnt; i += 256) {
        int d = sdst[i], s = ssrc[i];
        int b = d >> 8;
        int off = atomicAdd(&hist[b], 1);
        pairs[resv[b] + off] = ((unsigned)(d & 255) << 17) | (unsigned)s;
    }
}

// per bucket: count -> local scan -> rowse/invdeg -> place csr_src
__global__ __launch_bounds__(256) void sort_bucket_kernel(
    const unsigned int* __restrict__ pairs, const int* __restrict__ bcursor,
    int2* __restrict__ rowse, float* __restrict__ invdeg,
    int* __restrict__ csr_src, int nNodes) {
    __shared__ int lcnt[256];
    __shared__ int lrp[256];
    int tid = threadIdx.x;
    int base = blockIdx.x << 8;
    int nn = nNodes - base; if (nn > 256) nn = 256;
    lcnt[tid] = 0;
    __syncthreads();
    int e0 = blockIdx.x * BCAP;
    int e1 = e0 + bcursor[blockIdx.x];
    for (int i = e0 + tid; i < e1; i += 256)
        atomicAdd(&lcnt[pairs[i] >> 17], 1);
    __syncthreads();
    int v = lcnt[tid];
    lrp[tid] = v;
    __syncthreads();
#pragma unroll
    for (int off = 1; off < 256; off <<= 1) {
        int t = (tid >= off) ? lrp[tid - off] : 0;
        __syncthreads();
        lrp[tid] += t;
        __syncthreads();
    }
    lcnt[tid] = 0;
    lrp[tid] = lrp[tid] - v + e0;  // exclusive start within padded bucket
    if (tid < nn) {
        rowse[base + tid] = make_int2(lrp[tid], lrp[tid] + v);
        invdeg[base + tid] = 1.0f / fmaxf((float)v, 1.0f);
    }
    __syncthreads();
    for (int i = e0 + tid; i < e1; i += 256) {
        unsigned pv = pairs[i];
        int j = (int)(pv >> 17);
        int off = atomicAdd(&lcnt[j], 1);
        csr_src[lrp[j] + off] = (int)(pv & 0x1FFFFu);
    }
}

// ---------------- fp32 -> bf16 converts ----------------
__global__ __launch_bounds__(256) void convert_x_kernel(const float* __restrict__ x,
                                                        ushort_t* __restrict__ xb, int n4) {
    int i = blockIdx.x * 256 + threadIdx.x;
    if (i >= n4) return;
    int e = i * 4;
    f32x4 v = __builtin_nontemporal_load((const f32x4*)(x + e));
    ushort4 o;
    o.x = f2bf(v.x); o.y = f2bf(v.y); o.z = f2bf(v.z); o.w = f2bf(v.w);
    *(ushort4*)(xb + e) = o;
}

// one launch for both weight transposes:
//   i < 65536           : Wt1[n][k] = k<128 ? Ws1[k][n] : Wn1[k-128][n]   (K-stack)
//   i >= 65536 (j)      : Wt2[n][k] = n<128 ? Ws2[k][n] : Wn2[k][n-128]   (N-stack)
__global__ __launch_bounds__(256) void wtrans_both_kernel(
    const float* __restrict__ Ws1, const float* __restrict__ Wn1,
    const float* __restrict__ Ws2, const float* __restrict__ Wn2,
    ushort_t* __restrict__ Wt1, ushort_t* __restrict__ Wt2) {
    int i = blockIdx.x * 256 + threadIdx.x;
    if (i < 65536) {
        int n = i >> 8, k = i & 255;
        float v = (k < 128) ? Ws1[(size_t)k * 256 + n] : Wn1[(size_t)(k - 128) * 256 + n];
        Wt1[(size_t)n * 256 + k] = f2bf(v);
    } else {
        int j = i - 65536;
        int n = j >> 8, k = j & 255;
        const float* W = (n < 128) ? Ws2 : Wn2;
        int nn = (n < 128) ? n : n - 128;
        Wt2[(size_t)n * 256 + k] = f2bf(W[(size_t)k * 128 + nn]);
    }
}

// ---------------- persistent dual-node gather (rowse int2) ------------------
#define ACC8(arr, v)                                                \
    arr[0] += bf2f((ushort_t)((v).x & 0xffffu));                    \
    arr[1] += bf2f((ushort_t)((v).x >> 16));                        \
    arr[2] += bf2f((ushort_t)((v).y & 0xffffu));                    \
    arr[3] += bf2f((ushort_t)((v).y >> 16));                        \
    arr[4] += bf2f((ushort_t)((v).z & 0xffffu));                    \
    arr[5] += bf2f((ushort_t)((v).z >> 16));                        \
    arr[6] += bf2f((ushort_t)((v).w & 0xffffu));                    \
    arr[7] += bf2f((ushort_t)((v).w >> 16));

// MODE 0: out bf16 [N][128] = mean  ; MODE 1: out f32 [N][128] = uself+bias+mean
template <int MODE>
__global__ __launch_bounds__(256) void gather2_kernel(
    const ushort_t* __restrict__ H,
    const int2* __restrict__ rowse,
    const int* __restrict__ csr_src,
    const float* __restrict__ invdeg,
    const ushort_t* __restrict__ uself,
    const float* __restrict__ bias,
    void* __restrict__ outp,
    int nNodes, int totWaves) {
    int lane = threadIdx.x & 63;
    int wv = blockIdx.x * 4 + (threadIdx.x >> 6);
    int grp = lane >> 4, sub = lane & 15;
    const size_t cofs = (size_t)sub * 8;
    int pair = wv;
    if (pair * 2 >= nNodes) return;
    int2 ra = rowse[pair * 2];
    int2 rb = rowse[pair * 2 + 1];  // N_NODES even -> nodeB always valid
    while (true) {
        int npair = pair + totWaves;
        bool hasNext = (npair * 2 < nNodes);
        int2 na = make_int2(0, 0), nb = make_int2(0, 0);
        if (hasNext) {  // prefetch next pair's meta; hides under H loads
            na = rowse[npair * 2];
            nb = rowse[npair * 2 + 1];
        }
        int nodeA = pair * 2;
        int sA = ra.x, eA = ra.y, sB = rb.x, eB = rb.y;
        int cA = sA, cB = sB;
        float accA[8] = {}, accB[8] = {};
        for (int ea = sA + grp, eb = sB + grp; ea < eA || eb < eB; ea += 16, eb += 16) {
            bool pa0 = ea < eA, pa1 = ea + 4 < eA, pa2 = ea + 8 < eA, pa3 = ea + 12 < eA;
            bool pb0 = eb < eB, pb1 = eb + 4 < eB, pb2 = eb + 8 < eB, pb3 = eb + 12 < eB;
            int ja0 = pa0 ? ea : cA, ja1 = pa1 ? ea + 4 : cA;
            int ja2 = pa2 ? ea + 8 : cA, ja3 = pa3 ? ea + 12 : cA;
            int jb0 = pb0 ? eb : cB, jb1 = pb1 ? eb + 4 : cB;
            int jb2 = pb2 ? eb + 8 : cB, jb3 = pb3 ? eb + 12 : cB;
            int sa0 = csr_src[ja0], sa1 = csr_src[ja1];
            int sa2 = csr_src[ja2], sa3 = csr_src[ja3];
            int sb0 = csr_src[jb0], sb1 = csr_src[jb1];
            int sb2 = csr_src[jb2], sb3 = csr_src[jb3];
            uint4 va0 = *(const uint4*)(H + (size_t)sa0 * 128 + cofs);
            uint4 va1 = *(const uint4*)(H + (size_t)sa1 * 128 + cofs);
            uint4 va2 = *(const uint4*)(H + (size_t)sa2 * 128 + cofs);
            uint4 va3 = *(const uint4*)(H + (size_t)sa3 * 128 + cofs);
            uint4 vb0 = *(const uint4*)(H + (size_t)sb0 * 128 + cofs);
            uint4 vb1 = *(const uint4*)(H + (size_t)sb1 * 128 + cofs);
            uint4 vb2 = *(const uint4*)(H + (size_t)sb2 * 128 + cofs);
            uint4 vb3 = *(const uint4*)(H + (size_t)sb3 * 128 + cofs);
            if (pa0) { ACC8(accA, va0); }
            if (pa1) { ACC8(accA, va1); }
            if (pa2) { ACC8(accA, va2); }
            if (pa3) { ACC8(accA, va3); }
            if (pb0) { ACC8(accB, vb0); }
            if (pb1) { ACC8(accB, vb1); }
            if (pb2) { ACC8(accB, vb2); }
            if (pb3) { ACC8(accB, vb3); }
        }
#pragma unroll
        for (int j = 0; j < 8; ++j) {
            accA[j] += __shfl_xor(accA[j], 16);
            accA[j] += __shfl_xor(accA[j], 32);
            accB[j] += __shfl_xor(accB[j], 16);
            accB[j] += __shfl_xor(accB[j], 32);
        }
        if (grp == 0) {
            int nodeB = nodeA + 1;
            float scA = invdeg[nodeA];
            float scB = invdeg[nodeB];
            if (MODE == 0) {
                uint4 o;
                o.x = (unsigned)f2bf(accA[0] * scA) | ((unsigned)f2bf(accA[1] * scA) << 16);
                o.y = (unsigned)f2bf(accA[2] * scA) | ((unsigned)f2bf(accA[3] * scA) << 16);
                o.z = (unsigned)f2bf(accA[4] * scA) | ((unsigned)f2bf(accA[5] * scA) << 16);
                o.w = (unsigned)f2bf(accA[6] * scA) | ((unsigned)f2bf(accA[7] * scA) << 16);
                *(uint4*)((ushort_t*)outp + (size_t)nodeA * 128 + cofs) = o;
                uint4 p2;
                p2.x = (unsigned)f2bf(accB[0] * scB) | ((unsigned)f2bf(accB[1] * scB) << 16);
                p2.y = (unsigned)f2bf(accB[2] * scB) | ((unsigned)f2bf(accB[3] * scB) << 16);
                p2.z = (unsigned)f2bf(accB[4] * scB) | ((unsigned)f2bf(accB[5] * scB) << 16);
                p2.w = (unsigned)f2bf(accB[6] * scB) | ((unsigned)f2bf(accB[7] * scB) << 16);
                *(uint4*)((ushort_t*)outp + (size_t)nodeB * 128 + cofs) = p2;
            } else {
                uint4 us = *(const uint4*)(uself + (size_t)nodeA * 128 + cofs);
                f32x4 o0, o1;
                o0.x = accA[0] * scA + bf2f((ushort_t)(us.x & 0xffffu)) + bias[cofs + 0];
                o0.y = accA[1] * scA + bf2f((ushort_t)(us.x >> 16)) + bias[cofs + 1];
                o0.z = accA[2] * scA + bf2f((ushort_t)(us.y & 0xffffu)) + bias[cofs + 2];
                o0.w = accA[3] * scA + bf2f((ushort_t)(us.y >> 16)) + bias[cofs + 3];
                o1.x = accA[4] * scA + bf2f((ushort_t)(us.z & 0xffffu)) + bias[cofs + 4];
                o1.y = accA[5] * scA + bf2f((ushort_t)(us.z >> 16)) + bias[cofs + 5];
                o1.z = accA[6] * scA + bf2f((ushort_t)(us.w & 0xffffu)) + bias[cofs + 6];
                o1.w = accA[7] * scA + bf2f((ushort_t)(us.w >> 16)) + bias[cofs + 7];
                float* op = (float*)outp + (size_t)nodeA * 128 + cofs;
                __builtin_nontemporal_store(o0, (f32x4*)op);
                __builtin_nontemporal_store(o1, (f32x4*)(op + 4));
                uint4 u2 = *(const uint4*)(uself + (size_t)nodeB * 128 + cofs);
                f32x4 q0, q1;
                q0.x = accB[0] * scB + bf2f((ushort_t)(u2.x & 0xffffu)) + bias[cofs + 0];
                q0.y = accB[1] * scB + bf2f((ushort_t)(u2.x >> 16)) + bias[cofs + 1];
                q0.z = accB[2] * scB + bf2f((ushort_t)(u2.y & 0xffffu)) + bias[cofs + 2];
                q0.w = accB[3] * scB + bf2f((ushort_t)(u2.y >> 16)) + bias[cofs + 3];
                q1.x = accB[4] * scB + bf2f((ushort_t)(u2.z & 0xffffu)) + bias[cofs + 4];
                q1.y = accB[5] * scB + bf2f((ushort_t)(u2.z >> 16)) + bias[cofs + 5];
                q1.z = accB[6] * scB + bf2f((ushort_t)(u2.w & 0xffffu)) + bias[cofs + 6];
                q1.w = accB[7] * scB + bf2f((ushort_t)(u2.w >> 16)) + bias[cofs + 7];
                float* oq = (float*)outp + (size_t)nodeB * 128 + cofs;
                __builtin_nontemporal_store(q0, (f32x4*)oq);
                __builtin_nontemporal_store(q1, (f32x4*)(oq + 4));
            }
        }
        if (!hasNext) break;
        pair = npair; ra = na; rb = nb;
    }
}

// ---------------- fused 2-layer GEMM, BM=64 (2 blocks/CU) -------------------
// Phase 1: h_tile[64][256] = sigmoid([xb|agg] @ Wt1 + b1)  -> LDS (swizzled)
// Phase 2: [uself|uneigh]  = h_tile @ Wt2                  -> global
// 512 threads, 8 waves (2x4 of 32x64). BK=32 double-buffered, stage(next)
// before MFMAs, one barrier per step. LDS 72KB -> 2 blocks/CU.
// Epilogue scratch in hs (dead after phase 2) — NOT Asb (round-15 OOB bug).
__global__ __launch_bounds__(512) void gemm_fused_kernel(
    const ushort_t* __restrict__ xb,    // [M][128]
    const ushort_t* __restrict__ agg,   // [M][128]
    const ushort_t* __restrict__ Wt1,   // [256][256] n-major
    const float* __restrict__ b1,
    const ushort_t* __restrict__ Wt2,   // [256][256] n-major
    ushort_t* __restrict__ uself,       // [M][128]
    ushort_t* __restrict__ uneigh,      // [M][128]
    int M) {
    __shared__ ushort_t hs[64 * 256];        // 32KB (row*256 + col^((row&7)<<3))
    __shared__ ushort_t Asb[2][64 * 32];     // 8KB
    __shared__ ushort_t Bsb[2][256 * 32];    // 32KB
    int tid = threadIdx.x;
    int lane = tid & 63, wid = tid >> 6;
    int l15 = lane & 15, kgrp = lane >> 4;
    int bm = blockIdx.x * 64;
    int wr = (wid >> 2) * 32, wc = (wid & 3) * 64;

    auto stageA = [&](int buf, int t) {
        if (wid >= 4) return;
        int k0 = t * 32;
        const ushort_t* Ap = (k0 < 128) ? xb : agg;
        int kk0 = k0 & 127;
        int row = wid * 16 + (lane >> 2);
        int scol = ((lane & 3) ^ (row & 3)) << 3;
        int ar = bm + row; if (ar > M - 1) ar = M - 1;
        __builtin_amdgcn_global_load_lds(
            (const GAS void*)(Ap + (size_t)ar * 128 + kk0 + scol),
            (LAS void*)(&Asb[buf][wid * 512]), 16, 0, 0);
    };
    auto stageB = [&](int buf, int t, const ushort_t* Bt) {
        int k0 = t * 32;
#pragma unroll
        for (int t2 = 0; t2 < 2; ++t2) {
            int c = wid * 2 + t2;
            int row = c * 16 + (lane >> 2);
            int scol = ((lane & 3) ^ (row & 3)) << 3;
            __builtin_amdgcn_global_load_lds(
                (const GAS void*)(Bt + (size_t)row * 256 + k0 + scol),
                (LAS void*)(&Bsb[buf][c * 512]), 16, 0, 0);
        }
    };

    f32x4 acc[2][4] = {};

    // ---- phase 1: K over [xb|agg] ----
    stageA(0, 0); stageB(0, 0, Wt1);
    __syncthreads();
#pragma unroll
    for (int t = 0; t < 8; ++t) {
        int buf = t & 1;
        if (t < 7) { stageA(buf ^ 1, t + 1); stageB(buf ^ 1, t + 1, Wt1); }
        bf16x8 af[2], bfv[4];
#pragma unroll
        for (int mi = 0; mi < 2; ++mi) {
            int row = wr + mi * 16 + l15;
            af[mi] = *(const bf16x8*)(&Asb[buf][row * 32 + ((kgrp ^ (row & 3)) << 3)]);
        }
#pragma unroll
        for (int ni = 0; ni < 4; ++ni) {
            int row = wc + ni * 16 + l15;
            bfv[ni] = *(const bf16x8*)(&Bsb[buf][row * 32 + ((kgrp ^ (row & 3)) << 3)]);
        }
#pragma unroll
        for (int mi = 0; mi < 2; ++mi)
#pragma unroll
            for (int ni = 0; ni < 4; ++ni)
                acc[mi][ni] = __builtin_amdgcn_mfma_f32_16x16x32_bf16(
                    af[mi], bfv[ni], acc[mi][ni], 0, 0, 0);
        __syncthreads();
    }

    // ---- phase-1 epilogue: bias+sigmoid -> hs (swizzled), zero acc ----
#pragma unroll
    for (int mi = 0; mi < 2; ++mi) {
#pragma unroll
        for (int ni = 0; ni < 4; ++ni) {
            int hcol = wc + ni * 16 + l15;
            float bv = b1[hcol];
#pragma unroll
            for (int r = 0; r < 4; ++r) {
                float v = acc[mi][ni][r] + bv;
                v = 1.0f / (1.0f + __expf(-v));
                int lr = wr + mi * 16 + kgrp * 4 + r;
                hs[lr * 256 + (hcol ^ ((lr & 7) << 3))] = f2bf(v);
                acc[mi][ni][r] = 0.0f;
            }
        }
    }
    // ---- phase 2: u = h @ Wt2, A from hs ----
    stageB(0, 0, Wt2);
    __syncthreads();
#pragma unroll
    for (int t = 0; t < 8; ++t) {
        int buf = t & 1;
        if (t < 7) stageB(buf ^ 1, t + 1, Wt2);
        int k0 = t * 32;
        bf16x8 af[2], bfv[4];
#pragma unroll
        for (int mi = 0; mi < 2; ++mi) {
            int row = wr + mi * 16 + l15;
            int c = k0 + kgrp * 8;
            af[mi] = *(const bf16x8*)(&hs[row * 256 + (c ^ ((row & 7) << 3))]);
        }
#pragma unroll
        for (int ni = 0; ni < 4; ++ni) {
            int row = wc + ni * 16 + l15;
            bfv[ni] = *(const bf16x8*)(&Bsb[buf][row * 32 + ((kgrp ^ (row & 3)) << 3)]);
        }
#pragma unroll
        for (int mi = 0; mi < 2; ++mi)
#pragma unroll
            for (int ni = 0; ni < 4; ++ni)
                acc[mi][ni] = __builtin_amdgcn_mfma_f32_16x16x32_bf16(
                    af[mi], bfv[ni], acc[mi][ni], 0, 0, 0);
        __syncthreads();
    }

    // ---- final epilogue: per-wave per-mi 16x64 transpose slabs, dual store --
    ushort_t* my = hs + wid * 1024;
#pragma unroll
    for (int mi = 0; mi < 2; ++mi) {
#pragma unroll
        for (int ni = 0; ni < 4; ++ni) {
#pragma unroll
            for (int r = 0; r < 4; ++r) {
                int lr = kgrp * 4 + r;
                int lc = (ni * 16 + l15) ^ (kgrp << 3);
                my[lr * 64 + lc] = f2bf(acc[mi][ni][r]);
            }
        }
#pragma unroll
        for (int it = 0; it < 2; ++it) {
            int r2 = (lane >> 3) + it * 8;
            int swz = ((r2 >> 2) & 3) << 3;
            int c2 = ((lane & 7) << 3) ^ swz;
            bf16x8 vv = *(const bf16x8*)(&my[r2 * 64 + c2]);
            int grow = bm + wr + mi * 16 + r2;
            if (grow < M) {
                int gc = wc + (c2 ^ swz);
                ushort_t* dstp = (gc < 128)
                    ? uself + (size_t)grow * 128 + gc
                    : uneigh + (size_t)grow * 128 + (gc - 128);
                *(bf16x8*)dstp = vv;
            }
        }
    }
}

extern "C" void kernel_launch(void* const* d_in, const int* in_sizes, int n_in,
                              void* d_out, int out_size, void* d_ws, size_t ws_size,
                              hipStream_t stream) {
    const float* x        = (const float*)d_in[0];
    const int*   src      = (const int*)d_in[1];
    const int*   dst      = (const int*)d_in[2];
    const float* W_self1  = (const float*)d_in[3];
    const float* W_neigh1 = (const float*)d_in[4];
    const float* b1       = (const float*)d_in[5];
    const float* W_self2  = (const float*)d_in[6];
    const float* W_neigh2 = (const float*)d_in[7];
    const float* b2       = (const float*)d_in[8];
    float* out = (float*)d_out;

    // ---- workspace layout ----
    char* p = (char*)d_ws;
    auto alloc = [&](size_t bytes) { char* r = p; p += (bytes + 255) & ~(size_t)255; return r; };
    float*    invdeg   = (float*)alloc((size_t)N_NODES * 4);
    ushort_t* xb       = (ushort_t*)alloc((size_t)N_NODES * 128 * 2);
    ushort_t* agg      = (ushort_t*)alloc((size_t)N_NODES * 128 * 2);
    ushort_t* uself    = (ushort_t*)alloc((size_t)N_NODES * 128 * 2);
    ushort_t* uneigh   = (ushort_t*)alloc((size_t)N_NODES * 128 * 2);
    ushort_t* Wt1      = (ushort_t*)alloc((size_t)256 * 256 * 2);
    ushort_t* Wt2      = (ushort_t*)alloc((size_t)256 * 256 * 2);
    int2* rowse        = (int2*)alloc((size_t)N_NODES * 8);
    int* bcursor       = (int*)alloc((size_t)NBUCK * 4);
    unsigned int* pairs= (unsigned int*)alloc((size_t)NBUCK * BCAP * 4);
    int* csr_src       = (int*)alloc((size_t)NBUCK * BCAP * 4);

    // ---- converts ----
    convert_x_kernel<<<(N_NODES * F_IN / 4 + 255) / 256, 256, 0, stream>>>(
        x, xb, N_NODES * F_IN / 4);
    wtrans_both_kernel<<<(2 * 65536) / 256, 256, 0, stream>>>(
        W_self1, W_neigh1, W_self2, W_neigh2, Wt1, Wt2);

    // ---- CSR build: bin (padded buckets) -> sort(+rowse+invdeg) ----
    hipMemsetAsync(bcursor, 0, (size_t)NBUCK * sizeof(int), stream);
    bin_edges_kernel<<<(N_EDGES + CHUNK - 1) / CHUNK, 256, 0, stream>>>(
        src, dst, bcursor, pairs, N_EDGES);
    sort_bucket_kernel<<<NBUCK, 256, 0, stream>>>(
        pairs, bcursor, rowse, invdeg, csr_src, N_NODES);

    const int GATHER_BLOCKS = 2048;
    const int TOT_WAVES = GATHER_BLOCKS * 4;

    // ---- layer 1 gather, fused 2-layer GEMM, final gather ----
    gather2_kernel<0><<<GATHER_BLOCKS, 256, 0, stream>>>(
        xb, rowse, csr_src, invdeg, nullptr, nullptr, agg, N_NODES, TOT_WAVES);
    {
        dim3 grid((N_NODES + 63) / 64);
        gemm_fused_kernel<<<grid, 512, 0, stream>>>(
            xb, agg, Wt1, b1, Wt2, uself, uneigh, N_NODES);
    }
    gather2_kernel<1><<<GATHER_BLOCKS, 256, 0, stream>>>(
        uneigh, rowse, csr_src, invdeg, uself, b2, out, N_NODES, TOT_WAVES);
}